// Round 3
// baseline (436.127 us; speedup 1.0000x reference)
//
#include <hip/hip_runtime.h>

// B=16384, motions width=256, LAT=32, IN=288, H1=H2=512, MOE=8, OUT=128
// All GEMMs via v_mfma_f32_16x16x32_bf16. Weights transposed to [N][K] bf16 in ws.
// Single-LDS-buffer design: [h(512) | z(32)] per 64-row tile -> 2 blocks/CU.

typedef __attribute__((ext_vector_type(8))) short bf16x8;
typedef __attribute__((ext_vector_type(4))) float f32x4;
#define MFMA(a, b, c) __builtin_amdgcn_mfma_f32_16x16x32_bf16(a, b, c, 0, 0, 0)

#define STRIDE 552   // LDS row stride in bf16: 276 dw, 276%32=20 -> 2-way (free) frag reads

__device__ __forceinline__ float elu_f(float x) { return x > 0.f ? x : (__expf(x) - 1.f); }

__device__ __forceinline__ ushort f2bf(float f) {
    union { float f; unsigned u; } v; v.f = f;
    unsigned r = v.u + 0x7fffu + ((v.u >> 16) & 1u);   // RNE
    return (ushort)(r >> 16);
}
__device__ __forceinline__ float bf2f(ushort u) {
    union { unsigned u; float f; } v; v.u = ((unsigned)u) << 16;
    return v.f;
}

// ---------------- prep: xz = concat(motions, z) as bf16 [16384][288] ----------------
__global__ void prep_xz(const float* __restrict__ motions, const float* __restrict__ z,
                        ushort* __restrict__ xz) {
    int i = blockIdx.x * 256 + threadIdx.x;      // over 16384*72 float4 chunks
    int r = i / 72, c = i % 72;
    float4 v = (c < 64) ? ((const float4*)motions)[r * 64 + c]
                        : ((const float4*)z)[r * 8 + (c - 64)];
    ushort4 o;
    o.x = f2bf(v.x); o.y = f2bf(v.y); o.z = f2bf(v.z); o.w = f2bf(v.w);
    *(ushort4*)(xz + (size_t)r * 288 + c * 4) = o;
}

// ---------------- prep: transpose+convert  in[E][K][N] f32 -> out[E][N][K] bf16 ----------------
__global__ void prep_transpose(const float* __restrict__ in, ushort* __restrict__ out,
                               int K, int N) {
    __shared__ float tile[32][33];
    const int e = blockIdx.z;
    const float* inp = in + (size_t)e * K * N;
    ushort* outp = out + (size_t)e * N * K;
    const int k0 = blockIdx.x * 32, n0 = blockIdx.y * 32;
    const int tx = threadIdx.x, ty = threadIdx.y;  // 32 x 8
    #pragma unroll
    for (int i = 0; i < 4; ++i)
        tile[ty + i * 8][tx] = inp[(size_t)(k0 + ty + i * 8) * N + n0 + tx];
    __syncthreads();
    #pragma unroll
    for (int i = 0; i < 4; ++i)
        outp[(size_t)(n0 + ty + i * 8) * K + k0 + tx] = f2bf(tile[tx][ty + i * 8]);
}

// ---------------- gate MLP (MFMA layers 1-2, scalar layer 3) ----------------
__global__ __launch_bounds__(512, 4) void gate_kernel(
    const ushort* __restrict__ xz,
    const ushort* __restrict__ gw1t, const float* __restrict__ gb1,
    const ushort* __restrict__ gw2t, const float* __restrict__ gb2,
    const float* __restrict__ gw3, const float* __restrict__ gb3,
    float* __restrict__ para, float* __restrict__ partial)
{
    __shared__ ushort hs[64 * STRIDE];
    __shared__ float red[512];
    const int t = threadIdx.x;
    const int lane = t & 63, w = t >> 6;
    const int lr = lane & 15, lk = lane >> 4;
    const int r0 = blockIdx.x * 64;
    const ushort* xrow = xz + (size_t)r0 * 288;
    const int n0 = w * 64;

    // L1: x[64,288] (A direct from global) @ gw1t^T -> hs[64,512]
    {
        f32x4 acc[4][4] = {};
        for (int ks = 0; ks < 9; ++ks) {
            bf16x8 a[4], b[4];
            #pragma unroll
            for (int mf = 0; mf < 4; ++mf)
                a[mf] = *(const bf16x8*)(xrow + (size_t)(mf * 16 + lr) * 288 + ks * 32 + lk * 8);
            #pragma unroll
            for (int nf = 0; nf < 4; ++nf)
                b[nf] = *(const bf16x8*)(gw1t + (size_t)(n0 + nf * 16 + lr) * 288 + ks * 32 + lk * 8);
            #pragma unroll
            for (int mf = 0; mf < 4; ++mf)
                #pragma unroll
                for (int nf = 0; nf < 4; ++nf)
                    acc[mf][nf] = MFMA(a[mf], b[nf], acc[mf][nf]);
        }
        #pragma unroll
        for (int nf = 0; nf < 4; ++nf) {
            int col = n0 + nf * 16 + lr;
            float bb = gb1[col];
            #pragma unroll
            for (int mf = 0; mf < 4; ++mf)
                #pragma unroll
                for (int j = 0; j < 4; ++j)
                    hs[(mf * 16 + lk * 4 + j) * STRIDE + col] = f2bf(elu_f(acc[mf][nf][j] + bb));
        }
    }
    __syncthreads();

    // L2: h1[64,512] @ gw2t^T -> regs -> hs[64,512]
    {
        f32x4 acc[4][4] = {};
        for (int ks = 0; ks < 16; ++ks) {
            bf16x8 a[4], b[4];
            #pragma unroll
            for (int mf = 0; mf < 4; ++mf)
                a[mf] = *(const bf16x8*)&hs[(mf * 16 + lr) * STRIDE + ks * 32 + lk * 8];
            #pragma unroll
            for (int nf = 0; nf < 4; ++nf)
                b[nf] = *(const bf16x8*)(gw2t + (size_t)(n0 + nf * 16 + lr) * 512 + ks * 32 + lk * 8);
            #pragma unroll
            for (int mf = 0; mf < 4; ++mf)
                #pragma unroll
                for (int nf = 0; nf < 4; ++nf)
                    acc[mf][nf] = MFMA(a[mf], b[nf], acc[mf][nf]);
        }
        __syncthreads();   // all L2 reads of h1 complete before overwrite
        #pragma unroll
        for (int nf = 0; nf < 4; ++nf) {
            int col = n0 + nf * 16 + lr;
            float bb = gb2[col];
            #pragma unroll
            for (int mf = 0; mf < 4; ++mf)
                #pragma unroll
                for (int j = 0; j < 4; ++j)
                    hs[(mf * 16 + lk * 4 + j) * STRIDE + col] = f2bf(elu_f(acc[mf][nf][j] + bb));
        }
    }
    __syncthreads();

    // L3: h2[64,512] @ gw3 [512,8] -> para, scalar (tiny)
    {
        const int row = t >> 3, e = t & 7;
        float acc = 0.f;
        for (int k = 0; k < 512; k += 8) {
            uint4 hv = *(const uint4*)&hs[row * STRIDE + k];
            acc += bf2f((ushort)(hv.x)) * gw3[(k + 0) * 8 + e];
            acc += bf2f((ushort)(hv.x >> 16)) * gw3[(k + 1) * 8 + e];
            acc += bf2f((ushort)(hv.y)) * gw3[(k + 2) * 8 + e];
            acc += bf2f((ushort)(hv.y >> 16)) * gw3[(k + 3) * 8 + e];
            acc += bf2f((ushort)(hv.z)) * gw3[(k + 4) * 8 + e];
            acc += bf2f((ushort)(hv.z >> 16)) * gw3[(k + 5) * 8 + e];
            acc += bf2f((ushort)(hv.w)) * gw3[(k + 6) * 8 + e];
            acc += bf2f((ushort)(hv.w >> 16)) * gw3[(k + 7) * 8 + e];
        }
        float p = elu_f(acc + gb3[e]);
        para[(size_t)(r0 + row) * 8 + e] = p;
        red[t] = p * p;
    }
    __syncthreads();
    for (int s = 256; s >= 1; s >>= 1) {
        if (t < s) red[t] += red[t + s];
        __syncthreads();
    }
    if (t == 0) partial[blockIdx.x] = red[0];
}

// ---------------- finalize: inv_norm ----------------
__global__ void finalize_kernel(const float* __restrict__ partial, float* __restrict__ invn) {
    __shared__ float red[256];
    const int t = threadIdx.x;
    red[t] = partial[t];
    __syncthreads();
    for (int s = 128; s >= 1; s >>= 1) {
        if (t < s) red[t] += red[t + s];
        __syncthreads();
    }
    if (t == 0) invn[0] = 1.0f / sqrtf(red[0]);
}

// ---------------- experts: 64 rows/block, loop 8 experts, single LDS buffer ----------------
__global__ __launch_bounds__(512, 4) void expert_kernel(
    const ushort* __restrict__ xz, const float* __restrict__ z,
    const ushort* __restrict__ W1t, const float* __restrict__ b1,
    const ushort* __restrict__ W2t, const float* __restrict__ b2,
    const ushort* __restrict__ W3t, const float* __restrict__ b3,
    const float* __restrict__ para, const float* __restrict__ invn,
    float* __restrict__ out)
{
    __shared__ ushort hs[64 * STRIDE];   // cols 0..511: h1/h2 (phased); cols 512..543: z (persistent)
    __shared__ float ps[64 * 8];
    const int t = threadIdx.x;
    const int lane = t & 63, w = t >> 6;
    const int lr = lane & 15, lk = lane >> 4;
    const int r0 = blockIdx.x * 64;
    const ushort* xrow = xz + (size_t)r0 * 288;
    const int n0 = w * 64;

    // stage z into cols 512..543 (written once; never overwritten)
    for (int i = t; i < 2048; i += 512) {
        int r = i >> 5, c = i & 31;
        hs[r * STRIDE + 512 + c] = f2bf(z[(size_t)(r0 + r) * 32 + c]);
    }
    ps[t] = para[(size_t)r0 * 8 + t];
    const float inv_norm = invn[0];

    float oacc[4][4];
    #pragma unroll
    for (int mf = 0; mf < 4; ++mf)
        #pragma unroll
        for (int j = 0; j < 4; ++j) oacc[mf][j] = 0.f;

    for (int e = 0; e < 8; ++e) {
        __syncthreads();   // prev expert L3 reads done; z/ps staged (e==0)

        // ---- L1: x[64,288] (A from global) @ W1t^T -> hs[64,512] ----
        {
            const ushort* Wt = W1t + (size_t)e * 512 * 288;
            f32x4 acc[4][4] = {};
            for (int ks = 0; ks < 9; ++ks) {
                bf16x8 a[4], b[4];
                #pragma unroll
                for (int mf = 0; mf < 4; ++mf)
                    a[mf] = *(const bf16x8*)(xrow + (size_t)(mf * 16 + lr) * 288 + ks * 32 + lk * 8);
                #pragma unroll
                for (int nf = 0; nf < 4; ++nf)
                    b[nf] = *(const bf16x8*)(Wt + (size_t)(n0 + nf * 16 + lr) * 288 + ks * 32 + lk * 8);
                #pragma unroll
                for (int mf = 0; mf < 4; ++mf)
                    #pragma unroll
                    for (int nf = 0; nf < 4; ++nf)
                        acc[mf][nf] = MFMA(a[mf], b[nf], acc[mf][nf]);
            }
            #pragma unroll
            for (int nf = 0; nf < 4; ++nf) {
                int col = n0 + nf * 16 + lr;
                float bb = b1[e * 512 + col];
                #pragma unroll
                for (int mf = 0; mf < 4; ++mf)
                    #pragma unroll
                    for (int j = 0; j < 4; ++j)
                        hs[(mf * 16 + lk * 4 + j) * STRIDE + col] = f2bf(elu_f(acc[mf][nf][j] + bb));
            }
        }
        __syncthreads();

        // ---- L2: [h1|z][64,544] @ W2t^T -> regs -> hs[64,512] ----
        {
            const ushort* Wt = W2t + (size_t)e * 512 * 544;
            f32x4 acc[4][4] = {};
            for (int ks = 0; ks < 17; ++ks) {   // ks=16 reads cols 512..543 = z (contiguous)
                bf16x8 a[4], b[4];
                #pragma unroll
                for (int mf = 0; mf < 4; ++mf)
                    a[mf] = *(const bf16x8*)&hs[(mf * 16 + lr) * STRIDE + ks * 32 + lk * 8];
                #pragma unroll
                for (int nf = 0; nf < 4; ++nf)
                    b[nf] = *(const bf16x8*)(Wt + (size_t)(n0 + nf * 16 + lr) * 544 + ks * 32 + lk * 8);
                #pragma unroll
                for (int mf = 0; mf < 4; ++mf)
                    #pragma unroll
                    for (int nf = 0; nf < 4; ++nf)
                        acc[mf][nf] = MFMA(a[mf], b[nf], acc[mf][nf]);
            }
            __syncthreads();   // all L2 reads of h1 complete before overwrite
            #pragma unroll
            for (int nf = 0; nf < 4; ++nf) {
                int col = n0 + nf * 16 + lr;
                float bb = b2[e * 512 + col];
                #pragma unroll
                for (int mf = 0; mf < 4; ++mf)
                    #pragma unroll
                    for (int j = 0; j < 4; ++j)
                        hs[(mf * 16 + lk * 4 + j) * STRIDE + col] = f2bf(elu_f(acc[mf][nf][j] + bb));
            }
        }
        __syncthreads();

        // ---- L3: [h2|z][64,544] @ W3t^T [128,544], gated accumulate ----
        {
            const ushort* Wt = W3t + (size_t)e * 128 * 544;
            f32x4 acc3[4] = {};
            const int c0 = w * 16;
            for (int ks = 0; ks < 17; ++ks) {
                bf16x8 b = *(const bf16x8*)(Wt + (size_t)(c0 + lr) * 544 + ks * 32 + lk * 8);
                #pragma unroll
                for (int mf = 0; mf < 4; ++mf) {
                    bf16x8 a = *(const bf16x8*)&hs[(mf * 16 + lr) * STRIDE + ks * 32 + lk * 8];
                    acc3[mf] = MFMA(a, b, acc3[mf]);
                }
            }
            float bb = b3[e * 128 + c0 + lr];
            #pragma unroll
            for (int mf = 0; mf < 4; ++mf)
                #pragma unroll
                for (int j = 0; j < 4; ++j) {
                    int row = mf * 16 + lk * 4 + j;
                    float h3 = elu_f(acc3[mf][j] + bb);
                    oacc[mf][j] += ps[row * 8 + e] * h3;
                }
        }
    }

    #pragma unroll
    for (int mf = 0; mf < 4; ++mf)
        #pragma unroll
        for (int j = 0; j < 4; ++j) {
            int row = mf * 16 + lk * 4 + j;
            float v = oacc[mf][j] * inv_norm;
            out[(size_t)(r0 + row) * 128 + w * 16 + lr] = 1.0f / (1.0f + __expf(-v));
        }
}

extern "C" void kernel_launch(void* const* d_in, const int* in_sizes, int n_in,
                              void* d_out, int out_size, void* d_ws, size_t ws_size,
                              hipStream_t stream) {
    const float* motions = (const float*)d_in[0];
    const float* z   = (const float*)d_in[1];
    const float* gw1 = (const float*)d_in[2];
    const float* gb1 = (const float*)d_in[3];
    const float* gw2 = (const float*)d_in[4];
    const float* gb2 = (const float*)d_in[5];
    const float* gw3 = (const float*)d_in[6];
    const float* gb3 = (const float*)d_in[7];
    const float* W1  = (const float*)d_in[8];
    const float* b1  = (const float*)d_in[9];
    const float* W2  = (const float*)d_in[10];
    const float* b2  = (const float*)d_in[11];
    const float* W3  = (const float*)d_in[12];
    const float* b3  = (const float*)d_in[13];
    float* out = (float*)d_out;

    char* W = (char*)d_ws;
    ushort* xz      = (ushort*)(W);              //  9,437,184 B
    ushort* gw1t    = (ushort*)(W + 9437184);    //    294,912
    ushort* gw2t    = (ushort*)(W + 9732096);    //    524,288
    ushort* W1t     = (ushort*)(W + 10256384);   //  2,359,296
    ushort* W2t     = (ushort*)(W + 12615680);   //  4,456,448
    ushort* W3t     = (ushort*)(W + 17072128);   //  1,114,112
    float*  para    = (float*) (W + 18186240);   //    524,288
    float*  partial = (float*) (W + 18710528);   //      1,024
    float*  invn    = (float*) (W + 18711552);   //          4

    prep_xz<<<dim3(4608), dim3(256), 0, stream>>>(motions, z, xz);
    prep_transpose<<<dim3(9, 16, 1), dim3(32, 8), 0, stream>>>(gw1, gw1t, 288, 512);
    prep_transpose<<<dim3(16, 16, 1), dim3(32, 8), 0, stream>>>(gw2, gw2t, 512, 512);
    prep_transpose<<<dim3(9, 16, 8), dim3(32, 8), 0, stream>>>(W1, W1t, 288, 512);
    prep_transpose<<<dim3(17, 16, 8), dim3(32, 8), 0, stream>>>(W2, W2t, 544, 512);
    prep_transpose<<<dim3(17, 4, 8), dim3(32, 8), 0, stream>>>(W3, W3t, 544, 128);

    gate_kernel<<<dim3(256), dim3(512), 0, stream>>>(xz, gw1t, gb1, gw2t, gb2, gw3, gb3,
                                                     para, partial);
    finalize_kernel<<<dim3(1), dim3(256), 0, stream>>>(partial, invn);
    expert_kernel<<<dim3(256), dim3(512), 0, stream>>>(xz, z, W1t, b1, W2t, b2, W3t, b3,
                                                       para, invn, out);
}

// Round 4
// 324.381 us; speedup vs baseline: 1.3445x; 1.3445x over previous
//
#include <hip/hip_runtime.h>

// B=16384, motions width=256, LAT=32, IN=288, H1=H2=512, MOE=8, OUT=128
// All GEMMs via v_mfma_f32_16x16x32_bf16. Weights transposed to [N][K] bf16 in ws.
// Single-LDS-buffer design: [h(512) | z(32)] per 64-row tile -> 2 blocks/CU.
// NOTE: __launch_bounds__(512,2) — arg2=4 empirically capped VGPR at 64 (spill disaster, R3).

typedef __attribute__((ext_vector_type(8))) short bf16x8;
typedef __attribute__((ext_vector_type(4))) float f32x4;
#define MFMA(a, b, c) __builtin_amdgcn_mfma_f32_16x16x32_bf16(a, b, c, 0, 0, 0)

#define STRIDE 552   // LDS row stride in bf16: 276 dw, 276%32=20 -> 2-way (free) frag reads

__device__ __forceinline__ float elu_f(float x) { return x > 0.f ? x : (__expf(x) - 1.f); }

__device__ __forceinline__ ushort f2bf(float f) {
    union { float f; unsigned u; } v; v.f = f;
    unsigned r = v.u + 0x7fffu + ((v.u >> 16) & 1u);   // RNE
    return (ushort)(r >> 16);
}
__device__ __forceinline__ float bf2f(ushort u) {
    union { unsigned u; float f; } v; v.u = ((unsigned)u) << 16;
    return v.f;
}

// ---------------- prep: xz = concat(motions, z) as bf16 [16384][288] ----------------
__global__ void prep_xz(const float* __restrict__ motions, const float* __restrict__ z,
                        ushort* __restrict__ xz) {
    int i = blockIdx.x * 256 + threadIdx.x;      // over 16384*72 float4 chunks
    int r = i / 72, c = i % 72;
    float4 v = (c < 64) ? ((const float4*)motions)[r * 64 + c]
                        : ((const float4*)z)[r * 8 + (c - 64)];
    ushort4 o;
    o.x = f2bf(v.x); o.y = f2bf(v.y); o.z = f2bf(v.z); o.w = f2bf(v.w);
    *(ushort4*)(xz + (size_t)r * 288 + c * 4) = o;
}

// ---------------- prep: transpose+convert  in[E][K][N] f32 -> out[E][N][K] bf16 ----------------
__global__ void prep_transpose(const float* __restrict__ in, ushort* __restrict__ out,
                               int K, int N) {
    __shared__ float tile[32][33];
    const int e = blockIdx.z;
    const float* inp = in + (size_t)e * K * N;
    ushort* outp = out + (size_t)e * N * K;
    const int k0 = blockIdx.x * 32, n0 = blockIdx.y * 32;
    const int tx = threadIdx.x, ty = threadIdx.y;  // 32 x 8
    #pragma unroll
    for (int i = 0; i < 4; ++i)
        tile[ty + i * 8][tx] = inp[(size_t)(k0 + ty + i * 8) * N + n0 + tx];
    __syncthreads();
    #pragma unroll
    for (int i = 0; i < 4; ++i)
        outp[(size_t)(n0 + ty + i * 8) * K + k0 + tx] = f2bf(tile[tx][ty + i * 8]);
}

// ---------------- gate MLP (MFMA layers 1-2, scalar layer 3) ----------------
__global__ __launch_bounds__(512, 2) void gate_kernel(
    const ushort* __restrict__ xz,
    const ushort* __restrict__ gw1t, const float* __restrict__ gb1,
    const ushort* __restrict__ gw2t, const float* __restrict__ gb2,
    const float* __restrict__ gw3, const float* __restrict__ gb3,
    float* __restrict__ para, float* __restrict__ partial)
{
    __shared__ ushort hs[64 * STRIDE];
    __shared__ float red[512];
    const int t = threadIdx.x;
    const int lane = t & 63, w = t >> 6;
    const int lr = lane & 15, lk = lane >> 4;
    const int r0 = blockIdx.x * 64;
    const ushort* xrow = xz + (size_t)r0 * 288;
    const int n0 = w * 64;

    // L1: x[64,288] (A direct from global) @ gw1t^T -> hs[64,512]
    {
        f32x4 acc[4][4] = {};
        for (int ks = 0; ks < 9; ++ks) {
            bf16x8 a[4], b[4];
            #pragma unroll
            for (int mf = 0; mf < 4; ++mf)
                a[mf] = *(const bf16x8*)(xrow + (size_t)(mf * 16 + lr) * 288 + ks * 32 + lk * 8);
            #pragma unroll
            for (int nf = 0; nf < 4; ++nf)
                b[nf] = *(const bf16x8*)(gw1t + (size_t)(n0 + nf * 16 + lr) * 288 + ks * 32 + lk * 8);
            #pragma unroll
            for (int mf = 0; mf < 4; ++mf)
                #pragma unroll
                for (int nf = 0; nf < 4; ++nf)
                    acc[mf][nf] = MFMA(a[mf], b[nf], acc[mf][nf]);
        }
        #pragma unroll
        for (int nf = 0; nf < 4; ++nf) {
            int col = n0 + nf * 16 + lr;
            float bb = gb1[col];
            #pragma unroll
            for (int mf = 0; mf < 4; ++mf)
                #pragma unroll
                for (int j = 0; j < 4; ++j)
                    hs[(mf * 16 + lk * 4 + j) * STRIDE + col] = f2bf(elu_f(acc[mf][nf][j] + bb));
        }
    }
    __syncthreads();

    // L2: h1[64,512] @ gw2t^T -> regs -> hs[64,512]
    {
        f32x4 acc[4][4] = {};
        for (int ks = 0; ks < 16; ++ks) {
            bf16x8 a[4], b[4];
            #pragma unroll
            for (int mf = 0; mf < 4; ++mf)
                a[mf] = *(const bf16x8*)&hs[(mf * 16 + lr) * STRIDE + ks * 32 + lk * 8];
            #pragma unroll
            for (int nf = 0; nf < 4; ++nf)
                b[nf] = *(const bf16x8*)(gw2t + (size_t)(n0 + nf * 16 + lr) * 512 + ks * 32 + lk * 8);
            #pragma unroll
            for (int mf = 0; mf < 4; ++mf)
                #pragma unroll
                for (int nf = 0; nf < 4; ++nf)
                    acc[mf][nf] = MFMA(a[mf], b[nf], acc[mf][nf]);
        }
        __syncthreads();   // all L2 reads of h1 complete before overwrite
        #pragma unroll
        for (int nf = 0; nf < 4; ++nf) {
            int col = n0 + nf * 16 + lr;
            float bb = gb2[col];
            #pragma unroll
            for (int mf = 0; mf < 4; ++mf)
                #pragma unroll
                for (int j = 0; j < 4; ++j)
                    hs[(mf * 16 + lk * 4 + j) * STRIDE + col] = f2bf(elu_f(acc[mf][nf][j] + bb));
        }
    }
    __syncthreads();

    // L3: h2[64,512] @ gw3 [512,8] -> para, scalar (tiny)
    {
        const int row = t >> 3, e = t & 7;
        float acc = 0.f;
        for (int k = 0; k < 512; k += 8) {
            uint4 hv = *(const uint4*)&hs[row * STRIDE + k];
            acc += bf2f((ushort)(hv.x)) * gw3[(k + 0) * 8 + e];
            acc += bf2f((ushort)(hv.x >> 16)) * gw3[(k + 1) * 8 + e];
            acc += bf2f((ushort)(hv.y)) * gw3[(k + 2) * 8 + e];
            acc += bf2f((ushort)(hv.y >> 16)) * gw3[(k + 3) * 8 + e];
            acc += bf2f((ushort)(hv.z)) * gw3[(k + 4) * 8 + e];
            acc += bf2f((ushort)(hv.z >> 16)) * gw3[(k + 5) * 8 + e];
            acc += bf2f((ushort)(hv.w)) * gw3[(k + 6) * 8 + e];
            acc += bf2f((ushort)(hv.w >> 16)) * gw3[(k + 7) * 8 + e];
        }
        float p = elu_f(acc + gb3[e]);
        para[(size_t)(r0 + row) * 8 + e] = p;
        red[t] = p * p;
    }
    __syncthreads();
    for (int s = 256; s >= 1; s >>= 1) {
        if (t < s) red[t] += red[t + s];
        __syncthreads();
    }
    if (t == 0) partial[blockIdx.x] = red[0];
}

// ---------------- finalize: inv_norm ----------------
__global__ void finalize_kernel(const float* __restrict__ partial, float* __restrict__ invn) {
    __shared__ float red[256];
    const int t = threadIdx.x;
    red[t] = partial[t];
    __syncthreads();
    for (int s = 128; s >= 1; s >>= 1) {
        if (t < s) red[t] += red[t + s];
        __syncthreads();
    }
    if (t == 0) invn[0] = 1.0f / sqrtf(red[0]);
}

// ---------------- experts: 64 rows/block, loop 8 experts, single LDS buffer ----------------
__global__ __launch_bounds__(512, 2) void expert_kernel(
    const ushort* __restrict__ xz, const float* __restrict__ z,
    const ushort* __restrict__ W1t, const float* __restrict__ b1,
    const ushort* __restrict__ W2t, const float* __restrict__ b2,
    const ushort* __restrict__ W3t, const float* __restrict__ b3,
    const float* __restrict__ para, const float* __restrict__ invn,
    float* __restrict__ out)
{
    __shared__ ushort hs[64 * STRIDE];   // cols 0..511: h1/h2 (phased); cols 512..543: z (persistent)
    __shared__ float ps[64 * 8];
    const int t = threadIdx.x;
    const int lane = t & 63, w = t >> 6;
    const int lr = lane & 15, lk = lane >> 4;
    const int r0 = blockIdx.x * 64;
    const ushort* xrow = xz + (size_t)r0 * 288;
    const int n0 = w * 64;

    // stage z into cols 512..543 (written once; never overwritten)
    for (int i = t; i < 2048; i += 512) {
        int r = i >> 5, c = i & 31;
        hs[r * STRIDE + 512 + c] = f2bf(z[(size_t)(r0 + r) * 32 + c]);
    }
    ps[t] = para[(size_t)r0 * 8 + t];
    const float inv_norm = invn[0];

    float oacc[4][4];
    #pragma unroll
    for (int mf = 0; mf < 4; ++mf)
        #pragma unroll
        for (int j = 0; j < 4; ++j) oacc[mf][j] = 0.f;

    for (int e = 0; e < 8; ++e) {
        __syncthreads();   // prev expert L3 reads done; z/ps staged (e==0)

        // ---- L1: x[64,288] (A from global) @ W1t^T -> hs[64,512] ----
        {
            const ushort* Wt = W1t + (size_t)e * 512 * 288;
            f32x4 acc[4][4] = {};
            for (int ks = 0; ks < 9; ++ks) {
                bf16x8 a[4], b[4];
                #pragma unroll
                for (int mf = 0; mf < 4; ++mf)
                    a[mf] = *(const bf16x8*)(xrow + (size_t)(mf * 16 + lr) * 288 + ks * 32 + lk * 8);
                #pragma unroll
                for (int nf = 0; nf < 4; ++nf)
                    b[nf] = *(const bf16x8*)(Wt + (size_t)(n0 + nf * 16 + lr) * 288 + ks * 32 + lk * 8);
                #pragma unroll
                for (int mf = 0; mf < 4; ++mf)
                    #pragma unroll
                    for (int nf = 0; nf < 4; ++nf)
                        acc[mf][nf] = MFMA(a[mf], b[nf], acc[mf][nf]);
            }
            #pragma unroll
            for (int nf = 0; nf < 4; ++nf) {
                int col = n0 + nf * 16 + lr;
                float bb = b1[e * 512 + col];
                #pragma unroll
                for (int mf = 0; mf < 4; ++mf)
                    #pragma unroll
                    for (int j = 0; j < 4; ++j)
                        hs[(mf * 16 + lk * 4 + j) * STRIDE + col] = f2bf(elu_f(acc[mf][nf][j] + bb));
            }
        }
        __syncthreads();

        // ---- L2: [h1|z][64,544] @ W2t^T -> regs -> hs[64,512] ----
        {
            const ushort* Wt = W2t + (size_t)e * 512 * 544;
            f32x4 acc[4][4] = {};
            for (int ks = 0; ks < 17; ++ks) {   // ks=16 reads cols 512..543 = z (contiguous)
                bf16x8 a[4], b[4];
                #pragma unroll
                for (int mf = 0; mf < 4; ++mf)
                    a[mf] = *(const bf16x8*)&hs[(mf * 16 + lr) * STRIDE + ks * 32 + lk * 8];
                #pragma unroll
                for (int nf = 0; nf < 4; ++nf)
                    b[nf] = *(const bf16x8*)(Wt + (size_t)(n0 + nf * 16 + lr) * 544 + ks * 32 + lk * 8);
                #pragma unroll
                for (int mf = 0; mf < 4; ++mf)
                    #pragma unroll
                    for (int nf = 0; nf < 4; ++nf)
                        acc[mf][nf] = MFMA(a[mf], b[nf], acc[mf][nf]);
            }
            __syncthreads();   // all L2 reads of h1 complete before overwrite
            #pragma unroll
            for (int nf = 0; nf < 4; ++nf) {
                int col = n0 + nf * 16 + lr;
                float bb = b2[e * 512 + col];
                #pragma unroll
                for (int mf = 0; mf < 4; ++mf)
                    #pragma unroll
                    for (int j = 0; j < 4; ++j)
                        hs[(mf * 16 + lk * 4 + j) * STRIDE + col] = f2bf(elu_f(acc[mf][nf][j] + bb));
            }
        }
        __syncthreads();

        // ---- L3: [h2|z][64,544] @ W3t^T [128,544], gated accumulate ----
        {
            const ushort* Wt = W3t + (size_t)e * 128 * 544;
            f32x4 acc3[4] = {};
            const int c0 = w * 16;
            for (int ks = 0; ks < 17; ++ks) {
                bf16x8 b = *(const bf16x8*)(Wt + (size_t)(c0 + lr) * 544 + ks * 32 + lk * 8);
                #pragma unroll
                for (int mf = 0; mf < 4; ++mf) {
                    bf16x8 a = *(const bf16x8*)&hs[(mf * 16 + lr) * STRIDE + ks * 32 + lk * 8];
                    acc3[mf] = MFMA(a, b, acc3[mf]);
                }
            }
            float bb = b3[e * 128 + c0 + lr];
            #pragma unroll
            for (int mf = 0; mf < 4; ++mf)
                #pragma unroll
                for (int j = 0; j < 4; ++j) {
                    int row = mf * 16 + lk * 4 + j;
                    float h3 = elu_f(acc3[mf][j] + bb);
                    oacc[mf][j] += ps[row * 8 + e] * h3;
                }
        }
    }

    #pragma unroll
    for (int mf = 0; mf < 4; ++mf)
        #pragma unroll
        for (int j = 0; j < 4; ++j) {
            int row = mf * 16 + lk * 4 + j;
            float v = oacc[mf][j] * inv_norm;
            out[(size_t)(r0 + row) * 128 + w * 16 + lr] = 1.0f / (1.0f + __expf(-v));
        }
}

extern "C" void kernel_launch(void* const* d_in, const int* in_sizes, int n_in,
                              void* d_out, int out_size, void* d_ws, size_t ws_size,
                              hipStream_t stream) {
    const float* motions = (const float*)d_in[0];
    const float* z   = (const float*)d_in[1];
    const float* gw1 = (const float*)d_in[2];
    const float* gb1 = (const float*)d_in[3];
    const float* gw2 = (const float*)d_in[4];
    const float* gb2 = (const float*)d_in[5];
    const float* gw3 = (const float*)d_in[6];
    const float* gb3 = (const float*)d_in[7];
    const float* W1  = (const float*)d_in[8];
    const float* b1  = (const float*)d_in[9];
    const float* W2  = (const float*)d_in[10];
    const float* b2  = (const float*)d_in[11];
    const float* W3  = (const float*)d_in[12];
    const float* b3  = (const float*)d_in[13];
    float* out = (float*)d_out;

    char* W = (char*)d_ws;
    ushort* xz      = (ushort*)(W);              //  9,437,184 B
    ushort* gw1t    = (ushort*)(W + 9437184);    //    294,912
    ushort* gw2t    = (ushort*)(W + 9732096);    //    524,288
    ushort* W1t     = (ushort*)(W + 10256384);   //  2,359,296
    ushort* W2t     = (ushort*)(W + 12615680);   //  4,456,448
    ushort* W3t     = (ushort*)(W + 17072128);   //  1,114,112
    float*  para    = (float*) (W + 18186240);   //    524,288
    float*  partial = (float*) (W + 18710528);   //      1,024
    float*  invn    = (float*) (W + 18711552);   //          4

    prep_xz<<<dim3(4608), dim3(256), 0, stream>>>(motions, z, xz);
    prep_transpose<<<dim3(9, 16, 1), dim3(32, 8), 0, stream>>>(gw1, gw1t, 288, 512);
    prep_transpose<<<dim3(16, 16, 1), dim3(32, 8), 0, stream>>>(gw2, gw2t, 512, 512);
    prep_transpose<<<dim3(9, 16, 8), dim3(32, 8), 0, stream>>>(W1, W1t, 288, 512);
    prep_transpose<<<dim3(17, 16, 8), dim3(32, 8), 0, stream>>>(W2, W2t, 544, 512);
    prep_transpose<<<dim3(17, 4, 8), dim3(32, 8), 0, stream>>>(W3, W3t, 544, 128);

    gate_kernel<<<dim3(256), dim3(512), 0, stream>>>(xz, gw1t, gb1, gw2t, gb2, gw3, gb3,
                                                     para, partial);
    finalize_kernel<<<dim3(1), dim3(256), 0, stream>>>(partial, invn);
    expert_kernel<<<dim3(256), dim3(512), 0, stream>>>(xz, z, W1t, b1, W2t, b2, W3t, b3,
                                                       para, invn, out);
}

// Round 5
// 283.681 us; speedup vs baseline: 1.5374x; 1.1435x over previous
//
#include <hip/hip_runtime.h>

// B=16384, motions width=256, LAT=32, IN=288, H1=H2=512, MOE=8, OUT=128
// All GEMMs via v_mfma_f32_16x16x32_bf16. Weights transposed to [N][K] bf16 in ws.
// R5: 16 waves/block (1024 thr), 64 rows/block, x staged once in LDS, B-prefetch.
// NOTE __launch_bounds__ cap formula (measured R3/R4): cap = 2048/(waves_per_block*arg2).

typedef __attribute__((ext_vector_type(8))) short bf16x8;
typedef __attribute__((ext_vector_type(4))) float f32x4;
#define MFMA(a, b, c) __builtin_amdgcn_mfma_f32_16x16x32_bf16(a, b, c, 0, 0, 0)

#define STRIDE 552   // h|z row stride (bf16): 276 dw ≡ 20 mod 32 -> b128 reads 2-way (free)
#define XSTRIDE 296  // x row stride (bf16): 148 dw ≡ 20 mod 32 -> same property

__device__ __forceinline__ float elu_f(float x) { return x > 0.f ? x : (__expf(x) - 1.f); }

__device__ __forceinline__ ushort f2bf(float f) {
    union { float f; unsigned u; } v; v.f = f;
    unsigned r = v.u + 0x7fffu + ((v.u >> 16) & 1u);   // RNE
    return (ushort)(r >> 16);
}
__device__ __forceinline__ float bf2f(ushort u) {
    union { unsigned u; float f; } v; v.u = ((unsigned)u) << 16;
    return v.f;
}
__device__ __forceinline__ bf16x8 ldg8(const ushort* p) { return *(const bf16x8*)p; }

// ---------------- prep: xz = concat(motions, z) as bf16 [16384][288] ----------------
__global__ void prep_xz(const float* __restrict__ motions, const float* __restrict__ z,
                        ushort* __restrict__ xz) {
    int i = blockIdx.x * 256 + threadIdx.x;      // over 16384*72 float4 chunks
    int r = i / 72, c = i % 72;
    float4 v = (c < 64) ? ((const float4*)motions)[r * 64 + c]
                        : ((const float4*)z)[r * 8 + (c - 64)];
    ushort4 o;
    o.x = f2bf(v.x); o.y = f2bf(v.y); o.z = f2bf(v.z); o.w = f2bf(v.w);
    *(ushort4*)(xz + (size_t)r * 288 + c * 4) = o;
}

// ---------------- prep: transpose+convert  in[E][K][N] f32 -> out[E][N][K] bf16 ----------------
__global__ void prep_transpose(const float* __restrict__ in, ushort* __restrict__ out,
                               int K, int N) {
    __shared__ float tile[32][33];
    const int e = blockIdx.z;
    const float* inp = in + (size_t)e * K * N;
    ushort* outp = out + (size_t)e * N * K;
    const int k0 = blockIdx.x * 32, n0 = blockIdx.y * 32;
    const int tx = threadIdx.x, ty = threadIdx.y;  // 32 x 8
    #pragma unroll
    for (int i = 0; i < 4; ++i)
        tile[ty + i * 8][tx] = inp[(size_t)(k0 + ty + i * 8) * N + n0 + tx];
    __syncthreads();
    #pragma unroll
    for (int i = 0; i < 4; ++i)
        outp[(size_t)(n0 + ty + i * 8) * K + k0 + tx] = f2bf(tile[tx][ty + i * 8]);
}

// ---------------- gate MLP: 16 waves, MFMA layers 1-2, scalar layer 3 ----------------
__global__ __launch_bounds__(1024, 1) void gate_kernel(
    const ushort* __restrict__ xz,
    const ushort* __restrict__ gw1t, const float* __restrict__ gb1,
    const ushort* __restrict__ gw2t, const float* __restrict__ gb2,
    const float* __restrict__ gw3, const float* __restrict__ gb3,
    float* __restrict__ para, float* __restrict__ partial)
{
    __shared__ ushort hs[64 * STRIDE];
    __shared__ float red[512];
    const int t = threadIdx.x;
    const int lane = t & 63, w = t >> 6;       // 16 waves
    const int lr = lane & 15, lk = lane >> 4;
    const int r0 = blockIdx.x * 64;
    const ushort* xrow = xz + (size_t)r0 * 288;
    const int n0 = w * 32;                     // 16 waves x 32 cols = 512

    // L1: x[64,288] (A from global) @ gw1t^T -> hs[64,512]
    {
        const ushort* B0 = gw1t + (size_t)(n0 + lr) * 288 + lk * 8;
        const ushort* B1 = gw1t + (size_t)(n0 + 16 + lr) * 288 + lk * 8;
        f32x4 acc[4][2] = {};
        bf16x8 bc0 = ldg8(B0), bc1 = ldg8(B1);
        for (int ks = 0; ks < 9; ++ks) {
            bf16x8 bn0 = bc0, bn1 = bc1;
            if (ks < 8) { bn0 = ldg8(B0 + (ks + 1) * 32); bn1 = ldg8(B1 + (ks + 1) * 32); }
            bf16x8 a[4];
            #pragma unroll
            for (int mf = 0; mf < 4; ++mf)
                a[mf] = ldg8(xrow + (size_t)(mf * 16 + lr) * 288 + ks * 32 + lk * 8);
            #pragma unroll
            for (int mf = 0; mf < 4; ++mf) {
                acc[mf][0] = MFMA(a[mf], bc0, acc[mf][0]);
                acc[mf][1] = MFMA(a[mf], bc1, acc[mf][1]);
            }
            bc0 = bn0; bc1 = bn1;
        }
        #pragma unroll
        for (int nf = 0; nf < 2; ++nf) {
            int col = n0 + nf * 16 + lr;
            float bb = gb1[col];
            #pragma unroll
            for (int mf = 0; mf < 4; ++mf)
                #pragma unroll
                for (int j = 0; j < 4; ++j)
                    hs[(mf * 16 + lk * 4 + j) * STRIDE + col] = f2bf(elu_f(acc[mf][nf][j] + bb));
        }
    }
    __syncthreads();

    // L2: h1[64,512] @ gw2t^T -> regs -> hs[64,512]
    {
        const ushort* B0 = gw2t + (size_t)(n0 + lr) * 512 + lk * 8;
        const ushort* B1 = gw2t + (size_t)(n0 + 16 + lr) * 512 + lk * 8;
        f32x4 acc[4][2] = {};
        bf16x8 bc0 = ldg8(B0), bc1 = ldg8(B1);
        for (int ks = 0; ks < 16; ++ks) {
            bf16x8 bn0 = bc0, bn1 = bc1;
            if (ks < 15) { bn0 = ldg8(B0 + (ks + 1) * 32); bn1 = ldg8(B1 + (ks + 1) * 32); }
            bf16x8 a[4];
            #pragma unroll
            for (int mf = 0; mf < 4; ++mf)
                a[mf] = *(const bf16x8*)&hs[(mf * 16 + lr) * STRIDE + ks * 32 + lk * 8];
            #pragma unroll
            for (int mf = 0; mf < 4; ++mf) {
                acc[mf][0] = MFMA(a[mf], bc0, acc[mf][0]);
                acc[mf][1] = MFMA(a[mf], bc1, acc[mf][1]);
            }
            bc0 = bn0; bc1 = bn1;
        }
        __syncthreads();   // all L2 reads of h1 complete before overwrite
        #pragma unroll
        for (int nf = 0; nf < 2; ++nf) {
            int col = n0 + nf * 16 + lr;
            float bb = gb2[col];
            #pragma unroll
            for (int mf = 0; mf < 4; ++mf)
                #pragma unroll
                for (int j = 0; j < 4; ++j)
                    hs[(mf * 16 + lk * 4 + j) * STRIDE + col] = f2bf(elu_f(acc[mf][nf][j] + bb));
        }
    }
    __syncthreads();

    // L3: h2[64,512] @ gw3 [512,8] -> para, scalar (tiny; threads 0..511)
    if (t < 512) {
        const int row = t >> 3, e = t & 7;
        float acc = 0.f;
        for (int k = 0; k < 512; k += 8) {
            uint4 hv = *(const uint4*)&hs[row * STRIDE + k];
            acc += bf2f((ushort)(hv.x)) * gw3[(k + 0) * 8 + e];
            acc += bf2f((ushort)(hv.x >> 16)) * gw3[(k + 1) * 8 + e];
            acc += bf2f((ushort)(hv.y)) * gw3[(k + 2) * 8 + e];
            acc += bf2f((ushort)(hv.y >> 16)) * gw3[(k + 3) * 8 + e];
            acc += bf2f((ushort)(hv.z)) * gw3[(k + 4) * 8 + e];
            acc += bf2f((ushort)(hv.z >> 16)) * gw3[(k + 5) * 8 + e];
            acc += bf2f((ushort)(hv.w)) * gw3[(k + 6) * 8 + e];
            acc += bf2f((ushort)(hv.w >> 16)) * gw3[(k + 7) * 8 + e];
        }
        float p = elu_f(acc + gb3[e]);
        para[(size_t)(r0 + row) * 8 + e] = p;
        red[t] = p * p;
    }
    __syncthreads();
    for (int s = 256; s >= 1; s >>= 1) {
        if (t < s) red[t] += red[t + s];
        __syncthreads();
    }
    if (t == 0) partial[blockIdx.x] = red[0];
}

// ---------------- finalize: inv_norm ----------------
__global__ void finalize_kernel(const float* __restrict__ partial, float* __restrict__ invn) {
    __shared__ float red[256];
    const int t = threadIdx.x;
    red[t] = partial[t];
    __syncthreads();
    for (int s = 128; s >= 1; s >>= 1) {
        if (t < s) red[t] += red[t + s];
        __syncthreads();
    }
    if (t == 0) invn[0] = 1.0f / sqrtf(red[0]);
}

// ---------------- experts: 64 rows/block, 16 waves, loop 8 experts ----------------
__global__ __launch_bounds__(1024, 1) void expert_kernel(
    const ushort* __restrict__ xz, const float* __restrict__ z,
    const ushort* __restrict__ W1t, const float* __restrict__ b1,
    const ushort* __restrict__ W2t, const float* __restrict__ b2,
    const ushort* __restrict__ W3t, const float* __restrict__ b3,
    const float* __restrict__ para, const float* __restrict__ invn,
    float* __restrict__ out)
{
    __shared__ ushort hs[64 * STRIDE];   // cols 0..511: h1/h2 (phased); 512..543: z (persistent)
    __shared__ ushort xs[64 * XSTRIDE];  // x tile, staged once
    __shared__ float ps[64 * 8];
    const int t = threadIdx.x;
    const int lane = t & 63, w = t >> 6;       // 16 waves
    const int lr = lane & 15, lk = lane >> 4;
    const int r0 = blockIdx.x * 64;
    const int n0 = w * 32;                     // L1/L2 col base
    const int rb = (w >> 2) * 16;              // L3 row base
    const int c0 = (w & 3) * 32;               // L3 col base

    // stage x once: 64x288 ushorts = 2304 uint4
    for (int i = t; i < 2304; i += 1024) {
        int r = i / 36, c = i % 36;
        *(uint4*)&xs[r * XSTRIDE + c * 8] = *(const uint4*)(xz + (size_t)(r0 + r) * 288 + c * 8);
    }
    // stage z into hs cols 512..543 (never overwritten)
    for (int i = t; i < 2048; i += 1024) {
        int r = i >> 5, c = i & 31;
        hs[r * STRIDE + 512 + c] = f2bf(z[(size_t)(r0 + r) * 32 + c]);
    }
    if (t < 512) ps[t] = para[(size_t)r0 * 8 + t];
    const float inv_norm = invn[0];

    f32x4 oacc[2] = {};

    for (int e = 0; e < 8; ++e) {
        __syncthreads();   // prev expert L3 reads done; staging done (e==0)

        // ---- L1: x[64,288] (A from xs) @ W1t^T -> hs[64,512] ----
        {
            const ushort* Wt = W1t + (size_t)e * 512 * 288;
            const ushort* B0 = Wt + (size_t)(n0 + lr) * 288 + lk * 8;
            const ushort* B1 = Wt + (size_t)(n0 + 16 + lr) * 288 + lk * 8;
            f32x4 acc[4][2] = {};
            bf16x8 bc0 = ldg8(B0), bc1 = ldg8(B1);
            for (int ks = 0; ks < 9; ++ks) {
                bf16x8 bn0 = bc0, bn1 = bc1;
                if (ks < 8) { bn0 = ldg8(B0 + (ks + 1) * 32); bn1 = ldg8(B1 + (ks + 1) * 32); }
                bf16x8 a[4];
                #pragma unroll
                for (int mf = 0; mf < 4; ++mf)
                    a[mf] = *(const bf16x8*)&xs[(mf * 16 + lr) * XSTRIDE + ks * 32 + lk * 8];
                #pragma unroll
                for (int mf = 0; mf < 4; ++mf) {
                    acc[mf][0] = MFMA(a[mf], bc0, acc[mf][0]);
                    acc[mf][1] = MFMA(a[mf], bc1, acc[mf][1]);
                }
                bc0 = bn0; bc1 = bn1;
            }
            #pragma unroll
            for (int nf = 0; nf < 2; ++nf) {
                int col = n0 + nf * 16 + lr;
                float bb = b1[e * 512 + col];
                #pragma unroll
                for (int mf = 0; mf < 4; ++mf)
                    #pragma unroll
                    for (int j = 0; j < 4; ++j)
                        hs[(mf * 16 + lk * 4 + j) * STRIDE + col] = f2bf(elu_f(acc[mf][nf][j] + bb));
            }
        }
        __syncthreads();

        // ---- L2: [h1|z][64,544] @ W2t^T -> regs -> hs[64,512] ----
        {
            const ushort* Wt = W2t + (size_t)e * 512 * 544;
            const ushort* B0 = Wt + (size_t)(n0 + lr) * 544 + lk * 8;
            const ushort* B1 = Wt + (size_t)(n0 + 16 + lr) * 544 + lk * 8;
            f32x4 acc[4][2] = {};
            bf16x8 bc0 = ldg8(B0), bc1 = ldg8(B1);
            for (int ks = 0; ks < 17; ++ks) {   // ks=16 reads z cols (contiguous)
                bf16x8 bn0 = bc0, bn1 = bc1;
                if (ks < 16) { bn0 = ldg8(B0 + (ks + 1) * 32); bn1 = ldg8(B1 + (ks + 1) * 32); }
                bf16x8 a[4];
                #pragma unroll
                for (int mf = 0; mf < 4; ++mf)
                    a[mf] = *(const bf16x8*)&hs[(mf * 16 + lr) * STRIDE + ks * 32 + lk * 8];
                #pragma unroll
                for (int mf = 0; mf < 4; ++mf) {
                    acc[mf][0] = MFMA(a[mf], bc0, acc[mf][0]);
                    acc[mf][1] = MFMA(a[mf], bc1, acc[mf][1]);
                }
                bc0 = bn0; bc1 = bn1;
            }
            __syncthreads();   // all L2 reads of h1 complete before overwrite
            #pragma unroll
            for (int nf = 0; nf < 2; ++nf) {
                int col = n0 + nf * 16 + lr;
                float bb = b2[e * 512 + col];
                #pragma unroll
                for (int mf = 0; mf < 4; ++mf)
                    #pragma unroll
                    for (int j = 0; j < 4; ++j)
                        hs[(mf * 16 + lk * 4 + j) * STRIDE + col] = f2bf(elu_f(acc[mf][nf][j] + bb));
            }
        }
        __syncthreads();

        // ---- L3: [h2|z][64,544] @ W3t^T [128,544]: wave tile 16 rows x 32 cols ----
        {
            const ushort* Wt = W3t + (size_t)e * 128 * 544;
            const ushort* B0 = Wt + (size_t)(c0 + lr) * 544 + lk * 8;
            const ushort* B1 = Wt + (size_t)(c0 + 16 + lr) * 544 + lk * 8;
            f32x4 acc3[2] = {};
            bf16x8 bc0 = ldg8(B0), bc1 = ldg8(B1);
            for (int ks = 0; ks < 17; ++ks) {
                bf16x8 bn0 = bc0, bn1 = bc1;
                if (ks < 16) { bn0 = ldg8(B0 + (ks + 1) * 32); bn1 = ldg8(B1 + (ks + 1) * 32); }
                bf16x8 a = *(const bf16x8*)&hs[(rb + lr) * STRIDE + ks * 32 + lk * 8];
                acc3[0] = MFMA(a, bc0, acc3[0]);
                acc3[1] = MFMA(a, bc1, acc3[1]);
                bc0 = bn0; bc1 = bn1;
            }
            #pragma unroll
            for (int nf = 0; nf < 2; ++nf) {
                float bb = b3[e * 128 + c0 + nf * 16 + lr];
                #pragma unroll
                for (int j = 0; j < 4; ++j) {
                    int row = rb + lk * 4 + j;
                    float h3 = elu_f(acc3[nf][j] + bb);
                    oacc[nf][j] += ps[row * 8 + e] * h3;
                }
            }
        }
    }

    #pragma unroll
    for (int nf = 0; nf < 2; ++nf)
        #pragma unroll
        for (int j = 0; j < 4; ++j) {
            int row = rb + lk * 4 + j;
            float v = oacc[nf][j] * inv_norm;
            out[(size_t)(r0 + row) * 128 + c0 + nf * 16 + lr] = 1.0f / (1.0f + __expf(-v));
        }
}

extern "C" void kernel_launch(void* const* d_in, const int* in_sizes, int n_in,
                              void* d_out, int out_size, void* d_ws, size_t ws_size,
                              hipStream_t stream) {
    const float* motions = (const float*)d_in[0];
    const float* z   = (const float*)d_in[1];
    const float* gw1 = (const float*)d_in[2];
    const float* gb1 = (const float*)d_in[3];
    const float* gw2 = (const float*)d_in[4];
    const float* gb2 = (const float*)d_in[5];
    const float* gw3 = (const float*)d_in[6];
    const float* gb3 = (const float*)d_in[7];
    const float* W1  = (const float*)d_in[8];
    const float* b1  = (const float*)d_in[9];
    const float* W2  = (const float*)d_in[10];
    const float* b2  = (const float*)d_in[11];
    const float* W3  = (const float*)d_in[12];
    const float* b3  = (const float*)d_in[13];
    float* out = (float*)d_out;

    char* W = (char*)d_ws;
    ushort* xz      = (ushort*)(W);              //  9,437,184 B
    ushort* gw1t    = (ushort*)(W + 9437184);    //    294,912
    ushort* gw2t    = (ushort*)(W + 9732096);    //    524,288
    ushort* W1t     = (ushort*)(W + 10256384);   //  2,359,296
    ushort* W2t     = (ushort*)(W + 12615680);   //  4,456,448
    ushort* W3t     = (ushort*)(W + 17072128);   //  1,114,112
    float*  para    = (float*) (W + 18186240);   //    524,288
    float*  partial = (float*) (W + 18710528);   //      1,024
    float*  invn    = (float*) (W + 18711552);   //          4

    prep_xz<<<dim3(4608), dim3(256), 0, stream>>>(motions, z, xz);
    prep_transpose<<<dim3(9, 16, 1), dim3(32, 8), 0, stream>>>(gw1, gw1t, 288, 512);
    prep_transpose<<<dim3(16, 16, 1), dim3(32, 8), 0, stream>>>(gw2, gw2t, 512, 512);
    prep_transpose<<<dim3(9, 16, 8), dim3(32, 8), 0, stream>>>(W1, W1t, 288, 512);
    prep_transpose<<<dim3(17, 16, 8), dim3(32, 8), 0, stream>>>(W2, W2t, 544, 512);
    prep_transpose<<<dim3(17, 4, 8), dim3(32, 8), 0, stream>>>(W3, W3t, 544, 128);

    gate_kernel<<<dim3(256), dim3(1024), 0, stream>>>(xz, gw1t, gb1, gw2t, gb2, gw3, gb3,
                                                      para, partial);
    finalize_kernel<<<dim3(1), dim3(256), 0, stream>>>(partial, invn);
    expert_kernel<<<dim3(256), dim3(1024), 0, stream>>>(xz, z, W1t, b1, W2t, b2, W3t, b3,
                                                        para, invn, out);
}